// Round 4
// baseline (188.408 us; speedup 1.0000x reference)
//
#include <hip/hip_runtime.h>

// LocalAttention: 8-phase 256^2 bf16 MFMA QKV-GEMM (T2+T3+T4+T5) + m97 out-GEMM
// + LDS-free MFMA flash attention (swapped QK^T, V^T global layout).
// ws layout (bytes): xb[0,8M) w1b[8M,14M) wob[14M,16M) Q[16M,24M) K[24M,32M)
//                    VT[32M,40M) attn[40M,48M)   -- all bf16 (short)

#define S_LEN 2048
#define NH 16
#define DH 64
#define DM 1024
#define WIN 128
#define K_DIM 1024

typedef __attribute__((ext_vector_type(8))) short short8;
typedef __attribute__((ext_vector_type(4))) short short4_t;
typedef __attribute__((ext_vector_type(4))) float f32x4;
typedef __attribute__((ext_vector_type(16))) float f32x16;

__device__ __forceinline__ unsigned short f2bf(float f){
  unsigned u = __float_as_uint(f);
  u += 0x7fffu + ((u >> 16) & 1u);   // RTNE
  return (unsigned short)(u >> 16);
}
__device__ __forceinline__ unsigned pk2(float lo, float hi){
  return (unsigned)f2bf(lo) | ((unsigned)f2bf(hi) << 16);
}
__device__ __forceinline__ void async16(void* l, const void* g){
  __builtin_amdgcn_global_load_lds((const __attribute__((address_space(1))) void*)g,
                                   (__attribute__((address_space(3))) void*)l, 16, 0, 0);
}

#define FENCE asm volatile("" ::: "memory")
#define BAR   do { FENCE; __builtin_amdgcn_s_barrier(); FENCE; } while(0)
#define WAITV6 asm volatile("s_waitcnt vmcnt(6)" ::: "memory")
#define WAITV0 asm volatile("s_waitcnt vmcnt(0)" ::: "memory")

__global__ void cvt_bf16(const float* __restrict__ in, short* __restrict__ out, int n){
  int i = (blockIdx.x * blockDim.x + threadIdx.x) * 4;
  if (i >= n) return;
  float4 v = *(const float4*)(in + i);
  short4_t o;
  o.x = (short)f2bf(v.x); o.y = (short)f2bf(v.y);
  o.z = (short)f2bf(v.z); o.w = (short)f2bf(v.w);
  *(short4_t*)(out + i) = o;
}

// ===================== 8-phase 256x256 QKV GEMM =====================
// A [4096,1024], Bw [3072,1024] (both row-major, C = A*Bw^T), K=1024.
// LDS: A0,A1,B0,B1 tiles of 256x64 bf16 (32KB each) = 128KB. Swizzle: chunk^=(row&7).
// A halves: h0 = mq0 rows {[0,64)u[128,192)}, h1 = mq1 rows. B halves by nq.
// Stage slots (iter i): p1:A1h1(2i+1) p2:A0h0(2i+2) p3:B0h0(2i+2) p4:B0h1(2i+2)
//                       p5:A0h1(2i+2) p6:A1h0(2i+3) p7:B1h0(2i+3) p8:B1h1(2i+3)
// vmcnt(6) at p4/p8 (vmcnt(0) at p4 of last iter). Reads: p1:a0+b0 p2:b1 p3:a1 p4:-
__device__ __forceinline__ void stageA(short* ldsA, const short* A, int m0, int T, int H, int tid){
  #pragma unroll
  for (int j = 0; j < 2; ++j) {
    int off16 = j*512 + tid;
    int lrow = off16 >> 3, slin = off16 & 7;
    int g = (lrow & 63) + ((lrow >> 6) << 7) + H*64;
    int sg = slin ^ (lrow & 7);
    async16(ldsA + ((H*128 + lrow)*64 + slin*8),
            A + (size_t)(m0 + g)*K_DIM + T*64 + sg*8);
  }
}
__device__ __forceinline__ void stageB(short* ldsB, const short* Bw, int n0, int T, int H, int tid){
  #pragma unroll
  for (int j = 0; j < 2; ++j) {
    int off16 = j*512 + tid;
    int lrow = off16 >> 3, slin = off16 & 7;
    int g = ((lrow >> 5) << 6) + H*32 + (lrow & 31);
    int sg = slin ^ (lrow & 7);
    async16(ldsB + ((H*128 + lrow)*64 + slin*8),
            Bw + (size_t)(n0 + g)*K_DIM + T*64 + sg*8);
  }
}
__device__ __forceinline__ void ldA(const short* At, int wr, int lr, int lh, int mq, short8 a[4][2]){
  #pragma unroll
  for (int mm = 0; mm < 4; ++mm)
    #pragma unroll
    for (int kk = 0; kk < 2; ++kk)
      a[mm][kk] = *(const short8*)(At + (mq*128 + wr*64 + mm*16 + lr)*64 + (((kk*4 + lh) ^ (lr & 7))*8));
}
__device__ __forceinline__ void ldB(const short* Bt, int wc, int lr, int lh, int nq, short8 b[2][2]){
  #pragma unroll
  for (int nn = 0; nn < 2; ++nn)
    #pragma unroll
    for (int kk = 0; kk < 2; ++kk)
      b[nn][kk] = *(const short8*)(Bt + (nq*128 + wc*32 + nn*16 + lr)*64 + (((kk*4 + lh) ^ (lr & 7))*8));
}
__device__ __forceinline__ void mfma8(f32x4 acc[8][4], const short8 a[4][2], const short8 b[2][2], int mq, int nq){
  __builtin_amdgcn_s_setprio(1);
  #pragma unroll
  for (int mm = 0; mm < 4; ++mm)
    #pragma unroll
    for (int nn = 0; nn < 2; ++nn)
      #pragma unroll
      for (int kk = 0; kk < 2; ++kk)
        acc[mq*4+mm][nq*2+nn] =
          __builtin_amdgcn_mfma_f32_16x16x32_bf16(a[mm][kk], b[nn][kk], acc[mq*4+mm][nq*2+nn], 0, 0, 0);
  __builtin_amdgcn_s_setprio(0);
}

__global__ __launch_bounds__(512, 2) void gemm_qkv8(
    const short* __restrict__ A, const short* __restrict__ Bw,
    const float* __restrict__ bias,
    short* __restrict__ Qb, short* __restrict__ Kb, short* __restrict__ Vb)
{
  __shared__ short lds[65536];              // 128 KB
  short* A0 = lds;          short* A1 = lds + 16384;
  short* B0 = lds + 32768;  short* B1 = lds + 49152;
  int tid = threadIdx.x, lane = tid & 63, wid = tid >> 6;
  int wr = wid >> 2, wc = wid & 3, lr = lane & 15, lh = lane >> 4;
  int m0 = blockIdx.y * 256, n0 = blockIdx.x * 256;

  f32x4 acc[8][4] = {};
  short8 a[4][2], b0[2][2], b1[2][2];

  // prologue: tile0 full + tile1 {Ah0, Bh0, Bh1}
  stageA(A0, A, m0, 0, 0, tid);
  stageA(A0, A, m0, 0, 1, tid);
  stageB(B0, Bw, n0, 0, 0, tid);
  stageB(B0, Bw, n0, 0, 1, tid);
  stageA(A1, A, m0, 1, 0, tid);
  stageB(B1, Bw, n0, 1, 0, tid);
  stageB(B1, Bw, n0, 1, 1, tid);
  WAITV6; BAR;

  for (int i = 0; i < 8; ++i) {
    int t1 = 2*i + 1, t2 = 2*i + 2, t3 = 2*i + 3;
    bool more = (i < 7);
    // ---- p1: quadrant (0,0), buf0
    ldA(A0, wr, lr, lh, 0, a); ldB(B0, wc, lr, lh, 0, b0);
    stageA(A1, A, m0, t1, 1, tid);
    BAR; mfma8(acc, a, b0, 0, 0); BAR;
    // ---- p2: (0,1)
    ldB(B0, wc, lr, lh, 1, b1);
    if (more) stageA(A0, A, m0, t2, 0, tid);
    BAR; mfma8(acc, a, b1, 0, 1); BAR;
    // ---- p3: (1,1)
    ldA(A0, wr, lr, lh, 1, a);
    if (more) stageB(B0, Bw, n0, t2, 0, tid);
    BAR; mfma8(acc, a, b1, 1, 1); BAR;
    // ---- p4: (1,0)
    if (more) stageB(B0, Bw, n0, t2, 1, tid);
    BAR; mfma8(acc, a, b0, 1, 0);
    if (more) { WAITV6; } else { WAITV0; }
    BAR;
    // ---- p5: (0,0), buf1
    ldA(A1, wr, lr, lh, 0, a); ldB(B1, wc, lr, lh, 0, b0);
    if (more) stageA(A0, A, m0, t2, 1, tid);
    BAR; mfma8(acc, a, b0, 0, 0); BAR;
    // ---- p6: (0,1)
    ldB(B1, wc, lr, lh, 1, b1);
    if (more) stageA(A1, A, m0, t3, 0, tid);
    BAR; mfma8(acc, a, b1, 0, 1); BAR;
    // ---- p7: (1,1)
    ldA(A1, wr, lr, lh, 1, a);
    if (more) stageB(B1, Bw, n0, t3, 0, tid);
    BAR; mfma8(acc, a, b1, 1, 1); BAR;
    // ---- p8: (1,0)
    if (more) stageB(B1, Bw, n0, t3, 1, tid);
    BAR; mfma8(acc, a, b0, 1, 0);
    WAITV6; BAR;
  }

  // epilogue: bias + scatter to Q/K (row-major) and V^T; Q pre-scaled 1/8
  #pragma unroll
  for (int m = 0; m < 8; ++m) {
    #pragma unroll
    for (int n = 0; n < 4; ++n) {
      int col = n0 + wc*64 + n*16 + lr;
      float bv = bias[col];
      int which = col >> 10, cc = col & 1023;
      int h = cc >> 6, d = cc & 63;
      float scl = which == 0 ? 0.125f : 1.0f;
      #pragma unroll
      for (int r = 0; r < 4; ++r) {
        int grow = m0 + wr*128 + m*16 + lh*4 + r;   // C/D: col=lane&15, row=(lane>>4)*4+r
        int bb = grow >> 11, s = grow & 2047;
        float v = (acc[m][n][r] + bv) * scl;
        if (which == 2) {
          Vb[((size_t)(bb*NH + h)*DH + d)*S_LEN + s] = (short)f2bf(v);   // V^T
        } else {
          short* dst = which == 0 ? Qb : Kb;
          dst[(((size_t)bb*NH + h)*S_LEN + s)*DH + d] = (short)f2bf(v);
        }
      }
    }
  }
}

// ---------------- Out GEMM (m97 128^2): Out[4096,1024] = Attn*Wo^T + bo (fp32)
__global__ __launch_bounds__(256) void gemm_out(
    const short* __restrict__ A, const short* __restrict__ Bw,
    const float* __restrict__ bias, float* __restrict__ Out)
{
  __shared__ short As[128*32], Bs[128*32];
  int tid = threadIdx.x;
  int lane = tid & 63, wv = tid >> 6;
  int wr = wv >> 1, wc = wv & 1;
  int lr = lane & 15, lh = lane >> 4;
  int m0 = blockIdx.y * 128, n0 = blockIdx.x * 128;

  f32x4 acc[4][4] = {};
  for (int kt = 0; kt < K_DIM; kt += 32) {
    #pragma unroll
    for (int i = 0; i < 2; ++i) {
      int c = i*256 + tid;
      int row = c >> 2, col = (c & 3) << 3;
      async16(&As[c*8], A  + (size_t)(m0+row)*K_DIM + kt + col);
      async16(&Bs[c*8], Bw + (size_t)(n0+row)*K_DIM + kt + col);
    }
    __syncthreads();
    short8 af[4], bfr[4];
    #pragma unroll
    for (int m = 0; m < 4; ++m) af[m]  = *(const short8*)&As[(wr*64 + m*16 + lr)*32 + lh*8];
    #pragma unroll
    for (int n = 0; n < 4; ++n) bfr[n] = *(const short8*)&Bs[(wc*64 + n*16 + lr)*32 + lh*8];
    #pragma unroll
    for (int m = 0; m < 4; ++m)
      #pragma unroll
      for (int n = 0; n < 4; ++n)
        acc[m][n] = __builtin_amdgcn_mfma_f32_16x16x32_bf16(af[m], bfr[n], acc[m][n], 0, 0, 0);
    __syncthreads();
  }
  #pragma unroll
  for (int m = 0; m < 4; ++m) {
    #pragma unroll
    for (int n = 0; n < 4; ++n) {
      int col = n0 + wc*64 + n*16 + lr;
      float bv = bias[col];
      #pragma unroll
      for (int r = 0; r < 4; ++r) {
        int grow = m0 + wr*64 + m*16 + lh*4 + r;
        Out[(size_t)grow*DM + col] = acc[m][n][r] + bv;
      }
    }
  }
}

// ---------------- MFMA flash attention, LDS-free, swapped operands (verified r2).
__global__ __launch_bounds__(256) void attn_mfma(
    const short* __restrict__ Qb, const short* __restrict__ Kb,
    const short* __restrict__ VTb, short* __restrict__ Ob)
{
  int tid = threadIdx.x;
  int lane = tid & 63, wv = tid >> 6;
  int q31 = lane & 31, h2 = lane >> 5;
  int bh = blockIdx.y;
  int q0w = blockIdx.x * 128 + wv * 32;
  int qa = q0w + q31;

  const short* Qg = Qb  + (size_t)bh * S_LEN * DH;
  const short* Kg = Kb  + (size_t)bh * S_LEN * DH;
  const short* Vg = VTb + (size_t)bh * DH * S_LEN;

  short8 qf[4];
  #pragma unroll
  for (int kc = 0; kc < 4; ++kc)
    qf[kc] = *(const short8*)(Qg + (size_t)qa * DH + kc*16 + h2*8);

  int ks = q0w - WIN; if (ks < 0) ks = 0;
  int ke = q0w + 32 + WIN; if (ke > S_LEN) ke = S_LEN;

  f32x16 o0 = {}, o1 = {};
  float m = -1e37f, l = 0.f;

  for (int t0 = ks; t0 < ke; t0 += 32) {
    f32x16 s = {};
    #pragma unroll
    for (int kc = 0; kc < 4; ++kc) {
      short8 kf = *(const short8*)(Kg + (size_t)(t0 + q31) * DH + kc*16 + h2*8);
      s = __builtin_amdgcn_mfma_f32_32x32x16_bf16(kf, qf[kc], s, 0, 0, 0);
    }
    float p[16];
    float tm = -1e38f;
    #pragma unroll
    for (int r = 0; r < 16; ++r) {
      int key = t0 + (r & 3) + 8*(r >> 2) + 4*h2;
      bool ok = (key >= qa - WIN) && (key <= qa + WIN);
      p[r] = ok ? s[r] : -1e38f;
      tm = fmaxf(tm, p[r]);
    }
    tm = fmaxf(tm, __shfl_xor(tm, 32, 64));
    float mn = fmaxf(m, tm);
    float sc = __expf(m - mn);
    float ts = 0.f;
    #pragma unroll
    for (int r = 0; r < 16; ++r) { p[r] = __expf(p[r] - mn); ts += p[r]; }
    ts += __shfl_xor(ts, 32, 64);
    l = l * sc + ts;
    m = mn;
    #pragma unroll
    for (int r = 0; r < 16; ++r) { o0[r] *= sc; o1[r] *= sc; }

    #pragma unroll
    for (int kc2 = 0; kc2 < 2; ++kc2) {
      unsigned A1 = pk2(p[kc2*8+0], p[kc2*8+1]);
      unsigned A2 = pk2(p[kc2*8+2], p[kc2*8+3]);
      unsigned B1 = pk2(p[kc2*8+4], p[kc2*8+5]);
      unsigned B2 = pk2(p[kc2*8+6], p[kc2*8+7]);
      unsigned sA1 = (unsigned)__shfl_xor((int)A1, 32, 64);
      unsigned sA2 = (unsigned)__shfl_xor((int)A2, 32, 64);
      unsigned sB1 = (unsigned)__shfl_xor((int)B1, 32, 64);
      unsigned sB2 = (unsigned)__shfl_xor((int)B2, 32, 64);
      union { unsigned u[4]; short8 v; } pa;
      pa.u[0] = h2 ? sB1 : A1;
      pa.u[1] = h2 ? sB2 : A2;
      pa.u[2] = h2 ? B1 : sA1;
      pa.u[3] = h2 ? B2 : sA2;
      #pragma unroll
      for (int mt = 0; mt < 2; ++mt) {
        short8 vf = *(const short8*)(Vg + (size_t)(mt*32 + q31) * S_LEN + t0 + kc2*16 + h2*8);
        if (mt == 0) o0 = __builtin_amdgcn_mfma_f32_32x32x16_bf16(vf, pa.v, o0, 0, 0, 0);
        else         o1 = __builtin_amdgcn_mfma_f32_32x32x16_bf16(vf, pa.v, o1, 0, 0, 0);
      }
    }
  }

  float inv = 1.0f / l;
  int b = bh >> 4, hh = bh & 15;
  unsigned* Orow = (unsigned*)Ob + ((size_t)b*S_LEN + qa) * (DM/2) + hh*32;
  #pragma unroll
  for (int mt = 0; mt < 2; ++mt) {
    #pragma unroll
    for (int aa = 0; aa < 4; ++aa) {
      #pragma unroll
      for (int e = 0; e < 2; ++e) {
        int r = 4*aa + 2*e;
        float x0 = (mt ? o1[r]   : o0[r])   * inv;
        float x1 = (mt ? o1[r+1] : o0[r+1]) * inv;
        int d = 2*e + 8*aa + 4*h2 + 32*mt;
        Orow[d >> 1] = pk2(x0, x1);
      }
    }
  }
}

extern "C" void kernel_launch(void* const* d_in, const int* in_sizes, int n_in,
                              void* d_out, int out_size, void* d_ws, size_t ws_size,
                              hipStream_t stream) {
  const float* x  = (const float*)d_in[0];   // [2,2048,1024]
  const float* w1 = (const float*)d_in[1];   // [3072,1024]
  const float* b1 = (const float*)d_in[2];   // [3072]
  const float* wo = (const float*)d_in[3];   // [1024,1024]
  const float* bo = (const float*)d_in[4];   // [1024]
  float* out = (float*)d_out;

  char* ws = (char*)d_ws;
  short* xb  = (short*)(ws);
  short* w1b = (short*)(ws + (size_t)8*1024*1024);
  short* wob = (short*)(ws + (size_t)14*1024*1024);
  short* Qb  = (short*)(ws + (size_t)16*1024*1024);
  short* Kb  = (short*)(ws + (size_t)24*1024*1024);
  short* VTb = (short*)(ws + (size_t)32*1024*1024);
  short* Ab  = (short*)(ws + (size_t)40*1024*1024);

  cvt_bf16<<<dim3(4096), dim3(256), 0, stream>>>(x,  xb,  2*2048*1024);
  cvt_bf16<<<dim3(3072), dim3(256), 0, stream>>>(w1, w1b, 3072*1024);
  cvt_bf16<<<dim3(1024), dim3(256), 0, stream>>>(wo, wob, 1024*1024);
  gemm_qkv8<<<dim3(12, 16), dim3(512), 0, stream>>>(xb, w1b, b1, Qb, Kb, VTb);
  attn_mfma<<<dim3(16, 32), dim3(256), 0, stream>>>(Qb, Kb, VTb, Ab);
  gemm_out<<<dim3(8, 32), dim3(256), 0, stream>>>(Ab, wob, bo, out);
}

// Round 5
// 170.330 us; speedup vs baseline: 1.1061x; 1.1061x over previous
//
#include <hip/hip_runtime.h>
#include <hip/hip_bf16.h>

// LocalAttention: m97 128^2 bf16 MFMA GEMMs + LDS-free MFMA flash attention
// (swapped QK^T, V^T global layout). r2-verified qkv; 8-wave gemm_out; fused cvt.
// ws layout (bytes): xb[0,8M) w1b[8M,14M) wob[14M,16M) Q[16M,24M) K[24M,32M)
//                    VT[32M,40M) attn[40M,48M)   -- all bf16 (short)

#define S_LEN 2048
#define NH 16
#define DH 64
#define DM 1024
#define WIN 128
#define K_DIM 1024

typedef __attribute__((ext_vector_type(8))) short short8;
typedef __attribute__((ext_vector_type(4))) short short4_t;
typedef __attribute__((ext_vector_type(4))) float f32x4;
typedef __attribute__((ext_vector_type(16))) float f32x16;

__device__ __forceinline__ unsigned short f2bf(float f){
  unsigned u = __float_as_uint(f);
  u += 0x7fffu + ((u >> 16) & 1u);   // RTNE
  return (unsigned short)(u >> 16);
}
__device__ __forceinline__ unsigned pk2(float lo, float hi){
  __hip_bfloat162 h = __float22bfloat162_rn(float2{lo, hi});
  return *reinterpret_cast<unsigned*>(&h);   // v_cvt_pk_bf16_f32 path
}
__device__ __forceinline__ void async16(void* l, const void* g){
  __builtin_amdgcn_global_load_lds((const __attribute__((address_space(1))) void*)g,
                                   (__attribute__((address_space(3))) void*)l, 16, 0, 0);
}

// ---------------- fused fp32->bf16 converts (exact ranges, no tail)
__global__ void cvt_all(const float* __restrict__ x, const float* __restrict__ w1,
                        const float* __restrict__ wo,
                        short* __restrict__ xb, short* __restrict__ w1b,
                        short* __restrict__ wob){
  int b = blockIdx.x;
  const float* src; short* dst; int base;
  if (b < 4096)      { src = x;  dst = xb;  base = b; }
  else if (b < 7168) { src = w1; dst = w1b; base = b - 4096; }
  else               { src = wo; dst = wob; base = b - 7168; }
  int i = (base * 256 + threadIdx.x) * 4;
  float4 v = *(const float4*)(src + i);
  short4_t o;
  o.x = (short)f2bf(v.x); o.y = (short)f2bf(v.y);
  o.z = (short)f2bf(v.z); o.w = (short)f2bf(v.w);
  *(short4_t*)(dst + i) = o;
}

// ---------------- QKV GEMM (r2-verified m97 128^2): C[4096,3072] = X * W^T
// Q,K written [b][h][s][64] (Q pre-scaled by 1/8); V written TRANSPOSED [b][h][64][s].
__global__ __launch_bounds__(256) void gemm_qkv(
    const short* __restrict__ A, const short* __restrict__ Bw,
    const float* __restrict__ bias,
    short* __restrict__ Qb, short* __restrict__ Kb, short* __restrict__ Vb)
{
  __shared__ short As[128*32], Bs[128*32];
  int tid = threadIdx.x;
  int lane = tid & 63, wv = tid >> 6;
  int wr = wv >> 1, wc = wv & 1;
  int lr = lane & 15, lh = lane >> 4;
  int m0 = blockIdx.y * 128, n0 = blockIdx.x * 128;

  f32x4 acc[4][4] = {};
  for (int kt = 0; kt < K_DIM; kt += 32) {
    #pragma unroll
    for (int i = 0; i < 2; ++i) {
      int c = i*256 + tid;
      int row = c >> 2, col = (c & 3) << 3;
      async16(&As[c*8], A  + (size_t)(m0+row)*K_DIM + kt + col);
      async16(&Bs[c*8], Bw + (size_t)(n0+row)*K_DIM + kt + col);
    }
    __syncthreads();
    short8 af[4], bfr[4];
    #pragma unroll
    for (int m = 0; m < 4; ++m) af[m]  = *(const short8*)&As[(wr*64 + m*16 + lr)*32 + lh*8];
    #pragma unroll
    for (int n = 0; n < 4; ++n) bfr[n] = *(const short8*)&Bs[(wc*64 + n*16 + lr)*32 + lh*8];
    #pragma unroll
    for (int m = 0; m < 4; ++m)
      #pragma unroll
      for (int n = 0; n < 4; ++n)
        acc[m][n] = __builtin_amdgcn_mfma_f32_16x16x32_bf16(af[m], bfr[n], acc[m][n], 0, 0, 0);
    __syncthreads();
  }
  #pragma unroll
  for (int m = 0; m < 4; ++m) {
    #pragma unroll
    for (int n = 0; n < 4; ++n) {
      int col = n0 + wc*64 + n*16 + lr;
      float bv = bias[col];
      int which = col >> 10, cc = col & 1023;
      int h = cc >> 6, d = cc & 63;
      float scl = which == 0 ? 0.125f : 1.0f;   // fold 1/sqrt(Dh) into Q
      #pragma unroll
      for (int r = 0; r < 4; ++r) {
        int grow = m0 + wr*64 + m*16 + lh*4 + r;   // C/D: col=lane&15, row=(lane>>4)*4+r
        int b = grow >> 11, s = grow & 2047;
        float v = (acc[m][n][r] + bv) * scl;
        if (which == 2) {
          Vb[((size_t)(b*NH + h)*DH + d)*S_LEN + s] = (short)f2bf(v);   // V^T
        } else {
          short* dst = which == 0 ? Qb : Kb;
          dst[(((size_t)b*NH + h)*S_LEN + s)*DH + d] = (short)f2bf(v);
        }
      }
    }
  }
}

// ---------------- Out GEMM, 8-wave 128^2 (wave grid 2x4, frags 4x2):
// Out[4096,1024] = Attn[4096,1024] * Wo^T + bo (fp32 out). 256 blocks -> 8 waves/CU.
__global__ __launch_bounds__(512) void gemm_out(
    const short* __restrict__ A, const short* __restrict__ Bw,
    const float* __restrict__ bias, float* __restrict__ Out)
{
  __shared__ short As[128*32], Bs[128*32];
  int tid = threadIdx.x;
  int lane = tid & 63, wv = tid >> 6;        // 8 waves
  int wr = wv >> 2, wc = wv & 3;             // 2 x 4
  int lr = lane & 15, lh = lane >> 4;
  int m0 = blockIdx.y * 128, n0 = blockIdx.x * 128;

  f32x4 acc[4][2] = {};
  for (int kt = 0; kt < K_DIM; kt += 32) {
    int row = tid >> 2, col = (tid & 3) << 3;   // 512 thr x 16B = full 128x32 tile
    async16(&As[tid*8], A  + (size_t)(m0+row)*K_DIM + kt + col);
    async16(&Bs[tid*8], Bw + (size_t)(n0+row)*K_DIM + kt + col);
    __syncthreads();
    short8 af[4], bfr[2];
    #pragma unroll
    for (int m = 0; m < 4; ++m) af[m]  = *(const short8*)&As[(wr*64 + m*16 + lr)*32 + lh*8];
    #pragma unroll
    for (int n = 0; n < 2; ++n) bfr[n] = *(const short8*)&Bs[(wc*32 + n*16 + lr)*32 + lh*8];
    #pragma unroll
    for (int m = 0; m < 4; ++m)
      #pragma unroll
      for (int n = 0; n < 2; ++n)
        acc[m][n] = __builtin_amdgcn_mfma_f32_16x16x32_bf16(af[m], bfr[n], acc[m][n], 0, 0, 0);
    __syncthreads();
  }
  #pragma unroll
  for (int m = 0; m < 4; ++m) {
    #pragma unroll
    for (int n = 0; n < 2; ++n) {
      int col = n0 + wc*32 + n*16 + lr;
      float bv = bias[col];
      #pragma unroll
      for (int r = 0; r < 4; ++r) {
        int grow = m0 + wr*64 + m*16 + lh*4 + r;
        Out[(size_t)grow*DM + col] = acc[m][n][r] + bv;
      }
    }
  }
}

// ---------------- MFMA flash attention, LDS-free, swapped operands (r2-verified).
__global__ __launch_bounds__(256) void attn_mfma(
    const short* __restrict__ Qb, const short* __restrict__ Kb,
    const short* __restrict__ VTb, short* __restrict__ Ob)
{
  int tid = threadIdx.x;
  int lane = tid & 63, wv = tid >> 6;
  int q31 = lane & 31, h2 = lane >> 5;
  int bh = blockIdx.y;
  int q0w = blockIdx.x * 128 + wv * 32;
  int qa = q0w + q31;

  const short* Qg = Qb  + (size_t)bh * S_LEN * DH;
  const short* Kg = Kb  + (size_t)bh * S_LEN * DH;
  const short* Vg = VTb + (size_t)bh * DH * S_LEN;

  short8 qf[4];
  #pragma unroll
  for (int kc = 0; kc < 4; ++kc)
    qf[kc] = *(const short8*)(Qg + (size_t)qa * DH + kc*16 + h2*8);

  int ks = q0w - WIN; if (ks < 0) ks = 0;
  int ke = q0w + 32 + WIN; if (ke > S_LEN) ke = S_LEN;

  f32x16 o0 = {}, o1 = {};
  float m = -1e37f, l = 0.f;

  for (int t0 = ks; t0 < ke; t0 += 32) {
    f32x16 s = {};
    #pragma unroll
    for (int kc = 0; kc < 4; ++kc) {
      short8 kf = *(const short8*)(Kg + (size_t)(t0 + q31) * DH + kc*16 + h2*8);
      s = __builtin_amdgcn_mfma_f32_32x32x16_bf16(kf, qf[kc], s, 0, 0, 0);
    }
    float p[16];
    float tm = -1e38f;
    #pragma unroll
    for (int r = 0; r < 16; ++r) {
      int key = t0 + (r & 3) + 8*(r >> 2) + 4*h2;
      bool ok = (key >= qa - WIN) && (key <= qa + WIN);
      p[r] = ok ? s[r] : -1e38f;
      tm = fmaxf(tm, p[r]);
    }
    tm = fmaxf(tm, __shfl_xor(tm, 32, 64));
    float mn = fmaxf(m, tm);
    float sc = __expf(m - mn);
    float ts = 0.f;
    #pragma unroll
    for (int r = 0; r < 16; ++r) { p[r] = __expf(p[r] - mn); ts += p[r]; }
    ts += __shfl_xor(ts, 32, 64);
    l = l * sc + ts;
    m = mn;
    #pragma unroll
    for (int r = 0; r < 16; ++r) { o0[r] *= sc; o1[r] *= sc; }

    #pragma unroll
    for (int kc2 = 0; kc2 < 2; ++kc2) {
      unsigned A1 = pk2(p[kc2*8+0], p[kc2*8+1]);
      unsigned A2 = pk2(p[kc2*8+2], p[kc2*8+3]);
      unsigned B1 = pk2(p[kc2*8+4], p[kc2*8+5]);
      unsigned B2 = pk2(p[kc2*8+6], p[kc2*8+7]);
      unsigned sA1 = (unsigned)__shfl_xor((int)A1, 32, 64);
      unsigned sA2 = (unsigned)__shfl_xor((int)A2, 32, 64);
      unsigned sB1 = (unsigned)__shfl_xor((int)B1, 32, 64);
      unsigned sB2 = (unsigned)__shfl_xor((int)B2, 32, 64);
      union { unsigned u[4]; short8 v; } pa;
      pa.u[0] = h2 ? sB1 : A1;
      pa.u[1] = h2 ? sB2 : A2;
      pa.u[2] = h2 ? B1 : sA1;
      pa.u[3] = h2 ? B2 : sA2;
      #pragma unroll
      for (int mt = 0; mt < 2; ++mt) {
        short8 vf = *(const short8*)(Vg + (size_t)(mt*32 + q31) * S_LEN + t0 + kc2*16 + h2*8);
        if (mt == 0) o0 = __builtin_amdgcn_mfma_f32_32x32x16_bf16(vf, pa.v, o0, 0, 0, 0);
        else         o1 = __builtin_amdgcn_mfma_f32_32x32x16_bf16(vf, pa.v, o1, 0, 0, 0);
      }
    }
  }

  float inv = 1.0f / l;
  int b = bh >> 4, hh = bh & 15;
  unsigned* Orow = (unsigned*)Ob + ((size_t)b*S_LEN + qa) * (DM/2) + hh*32;
  #pragma unroll
  for (int mt = 0; mt < 2; ++mt) {
    #pragma unroll
    for (int aa = 0; aa < 4; ++aa) {
      #pragma unroll
      for (int e = 0; e < 2; ++e) {
        int r = 4*aa + 2*e;
        float x0 = (mt ? o1[r]   : o0[r])   * inv;
        float x1 = (mt ? o1[r+1] : o0[r+1]) * inv;
        int d = 2*e + 8*aa + 4*h2 + 32*mt;
        Orow[d >> 1] = pk2(x0, x1);
      }
    }
  }
}

extern "C" void kernel_launch(void* const* d_in, const int* in_sizes, int n_in,
                              void* d_out, int out_size, void* d_ws, size_t ws_size,
                              hipStream_t stream) {
  const float* x  = (const float*)d_in[0];   // [2,2048,1024]
  const float* w1 = (const float*)d_in[1];   // [3072,1024]
  const float* b1 = (const float*)d_in[2];   // [3072]
  const float* wo = (const float*)d_in[3];   // [1024,1024]
  const float* bo = (const float*)d_in[4];   // [1024]
  float* out = (float*)d_out;

  char* ws = (char*)d_ws;
  short* xb  = (short*)(ws);
  short* w1b = (short*)(ws + (size_t)8*1024*1024);
  short* wob = (short*)(ws + (size_t)14*1024*1024);
  short* Qb  = (short*)(ws + (size_t)16*1024*1024);
  short* Kb  = (short*)(ws + (size_t)24*1024*1024);
  short* VTb = (short*)(ws + (size_t)32*1024*1024);
  short* Ab  = (short*)(ws + (size_t)40*1024*1024);

  cvt_all<<<dim3(8192), dim3(256), 0, stream>>>(x, w1, wo, xb, w1b, wob);
  gemm_qkv<<<dim3(24, 32), dim3(256), 0, stream>>>(xb, w1b, b1, Qb, Kb, VTb);
  attn_mfma<<<dim3(16, 32), dim3(256), 0, stream>>>(Qb, Kb, VTb, Ab);
  gemm_out<<<dim3(8, 32), dim3(512), 0, stream>>>(Ab, wob, bo, out);
}